// Round 5
// baseline (54122.272 us; speedup 1.0000x reference)
//
#include <hip/hip_runtime.h>
#include <hip/hip_bf16.h>

// ---------------------------------------------------------------------------
// VQ-VAE transformer forward — Round 5: FLOAT32 outputs (reference returns
// jnp.float32; the 2.82 error signature matched bf16-written-into-f32-buffer).
// Compact 35 MB workspace, runtime input-dtype detect, fp32 internal math.
// Host-side in_sizes sanity check writes a 100.0 sentinel into mu on mismatch
// (diagnoses input-order assumption via the reported absmax).
// ---------------------------------------------------------------------------

using bf16 = __hip_bfloat16;

#define ENC_L 4
#define DEC_L 6
#define NH    8
#define DMODEL 512
#define DH    64
#define DFF   2048
#define DLAT  128
#define NTOK  1024
#define NCODES 2048
#define T_ENC 128
#define BT    8
#define NSEQ  16
#define T_DEC 1024
#define BENC  (BT*NSEQ)          // 128
#define EMB_SCALE 22.627416997969522f
#define LN10000 9.210340371976184f

#define ENC_CB 16                // batch entries per encoder chunk
#define DEC_CB 2                 // batch entries per decoder chunk
#define MC 2048                  // rows per chunk

__device__ __forceinline__ float ldw(const void* p, size_t i, int isbf) {
    return isbf ? __bfloat162float(((const bf16*)p)[i]) : ((const float*)p)[i];
}

// enc_ln1g is all ones: word0 0x3F800000 => f32, 0x3F803F80 => packed bf16
__global__ void detect_kernel(const unsigned int* __restrict__ g1,
                              int* __restrict__ flag, float* __restrict__ acc) {
    if (threadIdx.x == 0) {
        flag[0] = (g1[0] != 0x3F800000u) ? 1 : 0;
        acc[0] = 0.f;
    }
}

__global__ void fill_kernel(float* __restrict__ p, float v, int n) {
    int i = blockIdx.x * 256 + threadIdx.x;
    if (i < n) p[i] = v;
}

__global__ void add_kernel(const float* __restrict__ a, const float* __restrict__ b,
                           float* __restrict__ c, int n) {
    int i = blockIdx.x * 256 + threadIdx.x;
    if (i < n) c[i] = a[i] + b[i];
}

__global__ void copy_kernel(const float* __restrict__ src, float* __restrict__ dst, int n) {
    int i = blockIdx.x * 256 + threadIdx.x;
    if (i < n) dst[i] = src[i];
}

// chunk embed: local row = bl*T + t, global batch = bj0 + bl
__global__ void embed_kernel(const int* __restrict__ toks, const void* __restrict__ emb,
                             float* __restrict__ out, int T, int Bdim, int bj0, int CB,
                             const int* __restrict__ dflag) {
    int isbf = dflag[0];
    int idx = blockIdx.x * 256 + threadIdx.x;
    int total = CB * T * DMODEL;
    if (idx >= total) return;
    int row = idx / DMODEL;        // bl*T + t
    int d = idx - row * DMODEL;
    int bl = row / T;
    int t = row - bl * T;
    int tok = toks[t * Bdim + bj0 + bl];
    float v = ldw(emb, (size_t)tok * DMODEL + d, isbf) * EMB_SCALE;
    int j = d >> 1;
    float freq = expf(-(float)(2 * j) * (LN10000 / (float)DMODEL));
    float ang = (float)t * freq;
    v += (d & 1) ? cosf(ang) : sinf(ang);
    out[idx] = v;
}

// gather t=0 rows of the encoder chunk into AG at global batch rows
__global__ void gather_t0_kernel(const float* __restrict__ Xc, float* __restrict__ Ag,
                                 int bj0) {
    int bl = blockIdx.x;           // 0..ENC_CB-1
    int d = threadIdx.x;           // 0..255
    Ag[(size_t)(bj0 + bl) * DMODEL + d] = Xc[(size_t)bl * T_ENC * DMODEL + d];
    Ag[(size_t)(bj0 + bl) * DMODEL + d + 256] = Xc[(size_t)bl * T_ENC * DMODEL + d + 256];
}

#define GBM 64
#define GBN 64
#define GBK 16

// C[M,N] = act(A[M,K] @ W[woff..][K,N] + bias[boff..][N])
__global__ __launch_bounds__(256) void gemm_kernel(
    const float* __restrict__ A, const void* __restrict__ W, size_t woff,
    const void* __restrict__ bias, size_t boff, float* __restrict__ C,
    int M, int N, int K, int relu, const int* __restrict__ dflag)
{
    int isbf = dflag[0];
    __shared__ float As[GBK][GBM + 1];
    __shared__ float Ws[GBK][GBN];
    int tid = threadIdx.x;
    int tx = tid & 15, ty = tid >> 4;
    int row0 = blockIdx.y * GBM, col0 = blockIdx.x * GBN;
    float acc[4][4] = {};
    for (int k0 = 0; k0 < K; k0 += GBK) {
        for (int i = tid; i < GBM * GBK; i += 256) {
            int m = i >> 4, k = i & 15;
            int gr = row0 + m;
            As[k][m] = (gr < M) ? A[(size_t)gr * K + k0 + k] : 0.f;
        }
        for (int i = tid; i < GBK * GBN; i += 256) {
            int k = i >> 6, n = i & 63;
            Ws[k][n] = ldw(W, woff + (size_t)(k0 + k) * N + col0 + n, isbf);
        }
        __syncthreads();
        #pragma unroll
        for (int k = 0; k < GBK; k++) {
            float a[4], w[4];
            #pragma unroll
            for (int i = 0; i < 4; i++) a[i] = As[k][ty * 4 + i];
            #pragma unroll
            for (int j = 0; j < 4; j++) w[j] = Ws[k][tx * 4 + j];
            #pragma unroll
            for (int i = 0; i < 4; i++)
                #pragma unroll
                for (int j = 0; j < 4; j++) acc[i][j] += a[i] * w[j];
        }
        __syncthreads();
    }
    #pragma unroll
    for (int i = 0; i < 4; i++) {
        int gr = row0 + ty * 4 + i;
        if (gr >= M) continue;
        #pragma unroll
        for (int j = 0; j < 4; j++) {
            int gc = col0 + tx * 4 + j;
            float v = acc[i][j];
            if (bias) v += ldw(bias, boff + gc, isbf);
            if (relu) v = fmaxf(v, 0.f);
            C[(size_t)gr * N + gc] = v;
        }
    }
}

// logits chunk GEMM: local row r = bl*T_DEC + t; out row = t*BT + (b0+bl); f32 out
__global__ __launch_bounds__(256) void gemm_logits_kernel(
    const float* __restrict__ A, const void* __restrict__ W,
    const void* __restrict__ bias, float* __restrict__ C,
    int M, int N, int K, int b0, const int* __restrict__ dflag)
{
    int isbf = dflag[0];
    __shared__ float As[GBK][GBM + 1];
    __shared__ float Ws[GBK][GBN];
    int tid = threadIdx.x;
    int tx = tid & 15, ty = tid >> 4;
    int row0 = blockIdx.y * GBM, col0 = blockIdx.x * GBN;
    float acc[4][4] = {};
    for (int k0 = 0; k0 < K; k0 += GBK) {
        for (int i = tid; i < GBM * GBK; i += 256) {
            int m = i >> 4, k = i & 15;
            As[k][m] = A[(size_t)(row0 + m) * K + k0 + k];
        }
        for (int i = tid; i < GBK * GBN; i += 256) {
            int k = i >> 6, n = i & 63;
            Ws[k][n] = ldw(W, (size_t)(k0 + k) * N + col0 + n, isbf);
        }
        __syncthreads();
        #pragma unroll
        for (int k = 0; k < GBK; k++) {
            float a[4], w[4];
            #pragma unroll
            for (int i = 0; i < 4; i++) a[i] = As[k][ty * 4 + i];
            #pragma unroll
            for (int j = 0; j < 4; j++) w[j] = Ws[k][tx * 4 + j];
            #pragma unroll
            for (int i = 0; i < 4; i++)
                #pragma unroll
                for (int j = 0; j < 4; j++) acc[i][j] += a[i] * w[j];
        }
        __syncthreads();
    }
    #pragma unroll
    for (int i = 0; i < 4; i++) {
        int r = row0 + ty * 4 + i;                    // bl*1024 + t
        int out_row = ((r & (T_DEC - 1)) * BT) + b0 + (r >> 10);
        #pragma unroll
        for (int j = 0; j < 4; j++) {
            int gc = col0 + tx * 4 + j;
            C[(size_t)out_row * N + gc] = acc[i][j] + ldw(bias, gc, isbf);
        }
    }
}

// attention within chunk: one block per (t, bl, h); qkv rows local bl*T + t
__global__ __launch_bounds__(256) void attn_kernel(
    const float* __restrict__ qkv, float* __restrict__ out,
    int T, int causal)
{
    __shared__ float qv[DH];
    __shared__ float sc[1024];
    __shared__ float red[256];
    __shared__ float part[256];
    int t = blockIdx.x;
    int bh = blockIdx.y;
    int bl = bh / NH, h = bh - (bh / NH) * NH;
    int tid = threadIdx.x;
    size_t row = (size_t)bl * T + t;
    const float* qp = qkv + row * (3 * DMODEL) + h * DH;
    if (tid < DH) qv[tid] = qp[tid];
    __syncthreads();
    int Tlim = causal ? (t + 1) : T;
    float lmax = -1e30f;
    for (int s = tid; s < Tlim; s += 256) {
        const float* kp = qkv + ((size_t)bl * T + s) * (3 * DMODEL) + DMODEL + h * DH;
        float dsum = 0.f;
        #pragma unroll
        for (int d = 0; d < DH; d++) dsum += qv[d] * kp[d];
        dsum *= 0.125f;
        sc[s] = dsum;
        lmax = fmaxf(lmax, dsum);
    }
    red[tid] = lmax; __syncthreads();
    for (int o = 128; o > 0; o >>= 1) {
        if (tid < o) red[tid] = fmaxf(red[tid], red[tid + o]);
        __syncthreads();
    }
    float m = red[0]; __syncthreads();
    float lsum = 0.f;
    for (int s = tid; s < Tlim; s += 256) {
        float e = expf(sc[s] - m);
        sc[s] = e;
        lsum += e;
    }
    red[tid] = lsum; __syncthreads();
    for (int o = 128; o > 0; o >>= 1) {
        if (tid < o) red[tid] += red[tid + o];
        __syncthreads();
    }
    float inv = 1.f / red[0];
    int d = tid & 63, grp = tid >> 6;
    float a = 0.f;
    for (int s = grp; s < Tlim; s += 4)
        a += sc[s] * qkv[((size_t)bl * T + s) * (3 * DMODEL) + 2 * DMODEL + h * DH + d];
    part[tid] = a; __syncthreads();
    if (tid < 64) {
        float o = (part[tid] + part[tid + 64] + part[tid + 128] + part[tid + 192]) * inv;
        out[row * DMODEL + h * DH + tid] = o;
    }
}

// out = LN(a+c) * g[goff..] + b[goff..]
__global__ __launch_bounds__(256) void ln_res_kernel(
    const float* __restrict__ a, const float* __restrict__ c,
    const void* __restrict__ g, const void* __restrict__ be, size_t goff,
    float* __restrict__ out, const int* __restrict__ dflag)
{
    int isbf = dflag[0];
    __shared__ float red[256];
    int row = blockIdx.x, tid = threadIdx.x;
    size_t base = (size_t)row * DMODEL;
    float x0 = a[base + tid] + c[base + tid];
    float x1 = a[base + tid + 256] + c[base + tid + 256];
    red[tid] = x0 + x1; __syncthreads();
    for (int o = 128; o > 0; o >>= 1) {
        if (tid < o) red[tid] += red[tid + o];
        __syncthreads();
    }
    float mean = red[0] * (1.f / DMODEL); __syncthreads();
    float d0 = x0 - mean, d1 = x1 - mean;
    red[tid] = d0 * d0 + d1 * d1; __syncthreads();
    for (int o = 128; o > 0; o >>= 1) {
        if (tid < o) red[tid] += red[tid + o];
        __syncthreads();
    }
    float rstd = rsqrtf(red[0] * (1.f / DMODEL) + 1e-5f);
    out[base + tid] = d0 * rstd * ldw(g, goff + tid, isbf) + ldw(be, goff + tid, isbf);
    out[base + tid + 256] = d1 * rstd * ldw(g, goff + tid + 256, isbf) + ldw(be, goff + tid + 256, isbf);
}

__global__ __launch_bounds__(64) void vq_kernel(
    const float* __restrict__ mu, const void* __restrict__ codebook,
    float* __restrict__ z, float* __restrict__ acc, const int* __restrict__ dflag)
{
    int isbf = dflag[0];
    __shared__ float cb[NCODES * 2];
    __shared__ float red[64];
    int r = blockIdx.x, tid = threadIdx.x;
    for (int i = tid; i < NCODES * 2; i += 64) cb[i] = ldw(codebook, i, isbf);
    __syncthreads();
    float g0 = mu[r * DLAT + 2 * tid];
    float g1 = mu[r * DLAT + 2 * tid + 1];
    float gg = g0 * g0 + g1 * g1;
    float best = 3.4e38f; int bi = 0;
    for (int c = 0; c < NCODES; c++) {
        float c0 = cb[2 * c], c1 = cb[2 * c + 1];
        float d2 = (gg - 2.f * (g0 * c0 + g1 * c1)) + (c0 * c0 + c1 * c1);
        if (d2 < best) { best = d2; bi = c; }
    }
    float q0 = cb[2 * bi], q1 = cb[2 * bi + 1];
    z[r * DLAT + 2 * tid] = q0;
    z[r * DLAT + 2 * tid + 1] = q1;
    float dv = (q0 - g0) * (q0 - g0) + (q1 - g1) * (q1 - g1);
    red[tid] = dv; __syncthreads();
    for (int o = 32; o > 0; o >>= 1) {
        if (tid < o) red[tid] += red[tid + o];
        __syncthreads();
    }
    if (tid == 0) atomicAdd(acc, red[0]);
}

__global__ void diff_kernel(const float* __restrict__ acc, float* __restrict__ dst) {
    dst[0] = 2.f * acc[0] / 16384.f;
}

// seg scatter for one decoder chunk: dsc[(bl*T_DEC + t)*DLAT + d], b = b0+bl
__global__ __launch_bounds__(128) void seg_kernel(
    const int* __restrict__ pos, const float* __restrict__ z,
    float* __restrict__ dsc, int b0)
{
    int t = blockIdx.x, bl = blockIdx.y;
    int b = b0 + bl;
    __shared__ int sseg;
    if (threadIdx.x == 0) {
        int cnt = 0;
        for (int i = 0; i < NSEQ + 1; i++) cnt += (pos[b * (NSEQ + 1) + i] <= t) ? 1 : 0;
        sseg = cnt - 1;
    }
    __syncthreads();
    int seg = sseg;
    float v = 0.f;
    if (seg >= 0 && seg < NSEQ) v = z[(b * NSEQ + seg) * DLAT + threadIdx.x];
    dsc[((size_t)bl * T_DEC + t) * DLAT + threadIdx.x] = v;
}

extern "C" void kernel_launch(void* const* d_in, const int* in_sizes, int n_in,
                              void* d_out, int out_size, void* d_ws, size_t ws_size,
                              hipStream_t stream)
{
    const int*  enc_inp = (const int*)d_in[0];
    const int*  dec_inp = (const int*)d_in[1];
    const int*  seq_pos = (const int*)d_in[2];
    const void* emb   = d_in[3];
    const void* eWqkv = d_in[4];  const void* eWo  = d_in[5];
    const void* eln1g = d_in[6];  const void* eln1b = d_in[7];
    const void* eln2g = d_in[8];  const void* eln2b = d_in[9];
    const void* eW1   = d_in[10]; const void* eb1  = d_in[11];
    const void* eW2   = d_in[12]; const void* eb2  = d_in[13];
    const void* dWqkv = d_in[14]; const void* dWo  = d_in[15];
    const void* dln1g = d_in[16]; const void* dln1b = d_in[17];
    const void* dln2g = d_in[18]; const void* dln2b = d_in[19];
    const void* dW1   = d_in[20]; const void* db1  = d_in[21];
    const void* dW2   = d_in[22]; const void* db2  = d_in[23];
    const void* W_mu  = d_in[24]; const void* b_mu = d_in[25];
    const void* cbk   = d_in[26];
    const void* seg_W = d_in[27]; const void* seg_b = d_in[28];
    const void* W_out = d_in[29]; const void* b_out = d_in[30];

    float* outf = (float*)d_out;
    float* out_mu     = outf;
    float* out_z      = outf + 16384;
    float* out_diff   = outf + 32768;
    float* out_logits = outf + 32769;

    // ---- input-order sanity check (dict-order flat sizes) ----
    bool order_ok = (n_in == 31) &&
        in_sizes[0] == 16384 && in_sizes[1] == 8192 && in_sizes[2] == 136 &&
        in_sizes[3] == 524288 && in_sizes[4] == 3145728 && in_sizes[5] == 1048576 &&
        in_sizes[10] == 4194304 && in_sizes[14] == 4718592 && in_sizes[15] == 1572864 &&
        in_sizes[24] == 65536 && in_sizes[25] == 128 && in_sizes[26] == 4096 &&
        in_sizes[29] == 524288 && in_sizes[30] == 1024;
    if (!order_ok) {
        // diagnostic sentinel: reported absmax ~100 would mean the input-order
        // assumption (setup_inputs dict order) is wrong.
        fill_kernel<<<64, 256, 0, stream>>>(out_mu, 100.0f, 16384);
        return;
    }

    // ---- compact workspace layout (floats); total ~35 MB ----
    float* ws  = (float*)d_ws;
    float* XC  = ws;                    // [2048,512]  chunk stream
    float* SPC = ws + 1048576;          // [2048,512]  seg_proj chunk
    float* TIN = ws + 2097152;          // [2048,512]  dec layer input
    float* QKV = ws + 3145728;          // [2048,1536]
    float* AO  = ws + 6291456;          // [2048,512]
    float* H   = ws + 3145728;          // [2048,2048] overlays QKV+AO (FFN phase)
    float* P   = ws + 7340032;          // [2048,512]
    float* DSC = ws + 8388608;          // [2048,128]
    float* AG  = ws + 8650752;          // [128,512]
    float* MU  = ws + 8716288;          // [128,128]
    float* Z   = ws + 8732672;          // [128,128]
    float* ACC = ws + 8749056;          // [1]
    int*   FLG = (int*)(ws + 8749057);  // [1]

    detect_kernel<<<1, 64, 0, stream>>>((const unsigned int*)eln1g, FLG, ACC);

    // ================= encoder: 8 chunks × (embed → 4 layers → gather) ======
    for (int c = 0; c < BENC / ENC_CB; c++) {
        int bj0 = c * ENC_CB;
        embed_kernel<<<(MC * DMODEL + 255) / 256, 256, 0, stream>>>(
            enc_inp, emb, XC, T_ENC, BENC, bj0, ENC_CB, FLG);
        for (int i = 0; i < ENC_L; i++) {
            size_t oQ  = (size_t)i * DMODEL * 3 * DMODEL;
            size_t oO  = (size_t)i * DMODEL * DMODEL;
            size_t o1  = (size_t)i * DMODEL * DFF;
            size_t o2  = (size_t)i * DFF * DMODEL;
            size_t oLn = (size_t)i * DMODEL;
            size_t oB1 = (size_t)i * DFF;
            gemm_kernel<<<dim3(3 * DMODEL / GBN, MC / GBM), 256, 0, stream>>>(
                XC, eWqkv, oQ, nullptr, 0, QKV, MC, 3 * DMODEL, DMODEL, 0, FLG);
            attn_kernel<<<dim3(T_ENC, ENC_CB * NH), 256, 0, stream>>>(QKV, AO, T_ENC, 0);
            gemm_kernel<<<dim3(DMODEL / GBN, MC / GBM), 256, 0, stream>>>(
                AO, eWo, oO, nullptr, 0, P, MC, DMODEL, DMODEL, 0, FLG);
            ln_res_kernel<<<MC, 256, 0, stream>>>(XC, P, eln1g, eln1b, oLn, XC, FLG);
            gemm_kernel<<<dim3(DFF / GBN, MC / GBM), 256, 0, stream>>>(
                XC, eW1, o1, eb1, oB1, H, MC, DFF, DMODEL, 1, FLG);
            gemm_kernel<<<dim3(DMODEL / GBN, MC / GBM), 256, 0, stream>>>(
                H, eW2, o2, eb2, oLn, P, MC, DMODEL, DFF, 0, FLG);
            ln_res_kernel<<<MC, 256, 0, stream>>>(XC, P, eln2g, eln2b, oLn, XC, FLG);
        }
        gather_t0_kernel<<<ENC_CB, 256, 0, stream>>>(XC, AG, bj0);
    }

    // ================= VQ =================
    gemm_kernel<<<dim3(DLAT / GBN, BENC / GBM), 256, 0, stream>>>(
        AG, W_mu, 0, b_mu, 0, MU, BENC, DLAT, DMODEL, 0, FLG);
    vq_kernel<<<BENC, 64, 0, stream>>>(MU, cbk, Z, ACC, FLG);
    copy_kernel<<<64, 256, 0, stream>>>(MU, out_mu, 16384);
    copy_kernel<<<64, 256, 0, stream>>>(Z, out_z, 16384);
    diff_kernel<<<1, 1, 0, stream>>>(ACC, out_diff);

    // ================= decoder: 4 chunks × (seg → SP → embed → 6 layers → logits)
    for (int c = 0; c < BT / DEC_CB; c++) {
        int b0 = c * DEC_CB;
        seg_kernel<<<dim3(T_DEC, DEC_CB), 128, 0, stream>>>(seq_pos, Z, DSC, b0);
        gemm_kernel<<<dim3(DMODEL / GBN, MC / GBM), 256, 0, stream>>>(
            DSC, seg_W, 0, seg_b, 0, SPC, MC, DMODEL, DLAT, 0, FLG);
        embed_kernel<<<(MC * DMODEL + 255) / 256, 256, 0, stream>>>(
            dec_inp, emb, XC, T_DEC, BT, b0, DEC_CB, FLG);
        for (int i = 0; i < DEC_L; i++) {
            size_t oQ  = (size_t)i * DMODEL * 3 * DMODEL;
            size_t oO  = (size_t)i * DMODEL * DMODEL;
            size_t o1  = (size_t)i * DMODEL * DFF;
            size_t o2  = (size_t)i * DFF * DMODEL;
            size_t oLn = (size_t)i * DMODEL;
            size_t oB1 = (size_t)i * DFF;
            add_kernel<<<(MC * DMODEL + 255) / 256, 256, 0, stream>>>(XC, SPC, TIN, MC * DMODEL);
            gemm_kernel<<<dim3(3 * DMODEL / GBN, MC / GBM), 256, 0, stream>>>(
                TIN, dWqkv, oQ, nullptr, 0, QKV, MC, 3 * DMODEL, DMODEL, 0, FLG);
            attn_kernel<<<dim3(T_DEC, DEC_CB * NH), 256, 0, stream>>>(QKV, AO, T_DEC, 1);
            gemm_kernel<<<dim3(DMODEL / GBN, MC / GBM), 256, 0, stream>>>(
                AO, dWo, oO, nullptr, 0, P, MC, DMODEL, DMODEL, 0, FLG);
            ln_res_kernel<<<MC, 256, 0, stream>>>(TIN, P, dln1g, dln1b, oLn, TIN, FLG);
            gemm_kernel<<<dim3(DFF / GBN, MC / GBM), 256, 0, stream>>>(
                TIN, dW1, o1, db1, oB1, H, MC, DFF, DMODEL, 1, FLG);
            gemm_kernel<<<dim3(DMODEL / GBN, MC / GBM), 256, 0, stream>>>(
                H, dW2, o2, db2, oLn, P, MC, DMODEL, DFF, 0, FLG);
            ln_res_kernel<<<MC, 256, 0, stream>>>(TIN, P, dln2g, dln2b, oLn, XC, FLG);
        }
        gemm_logits_kernel<<<dim3(NTOK / GBN, MC / GBM), 256, 0, stream>>>(
            XC, W_out, b_out, out_logits, MC, NTOK, DMODEL, b0, FLG);
    }
}

// Round 6
// 41502.286 us; speedup vs baseline: 1.3041x; 1.3041x over previous
//
#include <hip/hip_runtime.h>
#include <hip/hip_bf16.h>

// ---------------------------------------------------------------------------
// VQ-VAE transformer forward — Round 6: all GEMMs moved to MFMA with
// split-bf16 (hi/lo) decomposition: C = Ah·Bh + Ah·Bl + Al·Bh (fp32-class
// accuracy, ~2^-16 rel err). 64x64x64 tiles, 4 waves, 16x16x32 bf16 MFMA.
// Attention/LN/elementwise unchanged from round 5 (next target).
// Outputs fp32; runtime input-dtype detect retained.
// ---------------------------------------------------------------------------

using bf16 = __hip_bfloat16;

#define ENC_L 4
#define DEC_L 6
#define NH    8
#define DMODEL 512
#define DH    64
#define DFF   2048
#define DLAT  128
#define NTOK  1024
#define NCODES 2048
#define T_ENC 128
#define BT    8
#define NSEQ  16
#define T_DEC 1024
#define BENC  (BT*NSEQ)          // 128
#define EMB_SCALE 22.627416997969522f
#define LN10000 9.210340371976184f

#define ENC_CB 16
#define DEC_CB 2
#define MC 2048                  // rows per chunk

typedef __attribute__((ext_vector_type(8))) short short8;
typedef __attribute__((ext_vector_type(4))) float floatx4;

__device__ __forceinline__ float ldw(const void* p, size_t i, int isbf) {
    return isbf ? __bfloat162float(((const bf16*)p)[i]) : ((const float*)p)[i];
}

__device__ __forceinline__ unsigned short f2bf_rne(float f) {
    unsigned int u = __float_as_uint(f);
    unsigned int r = (u + 0x7FFFu + ((u >> 16) & 1u)) >> 16;
    return (unsigned short)r;
}
__device__ __forceinline__ float bf2f(unsigned short s) {
    return __uint_as_float(((unsigned int)s) << 16);
}

// enc_ln1g is all ones: word0 0x3F800000 => f32, 0x3F803F80 => packed bf16
__global__ void detect_kernel(const unsigned int* __restrict__ g1,
                              int* __restrict__ flag, float* __restrict__ acc) {
    if (threadIdx.x == 0) {
        flag[0] = (g1[0] != 0x3F800000u) ? 1 : 0;
        acc[0] = 0.f;
    }
}

__global__ void fill_kernel(float* __restrict__ p, float v, int n) {
    int i = blockIdx.x * 256 + threadIdx.x;
    if (i < n) p[i] = v;
}

__global__ void add_kernel(const float* __restrict__ a, const float* __restrict__ b,
                           float* __restrict__ c, int n) {
    int i = blockIdx.x * 256 + threadIdx.x;
    if (i < n) c[i] = a[i] + b[i];
}

__global__ void copy_kernel(const float* __restrict__ src, float* __restrict__ dst, int n) {
    int i = blockIdx.x * 256 + threadIdx.x;
    if (i < n) dst[i] = src[i];
}

// chunk embed: local row = bl*T + t, global batch = bj0 + bl
__global__ void embed_kernel(const int* __restrict__ toks, const void* __restrict__ emb,
                             float* __restrict__ out, int T, int Bdim, int bj0, int CB,
                             const int* __restrict__ dflag) {
    int isbf = dflag[0];
    int idx = blockIdx.x * 256 + threadIdx.x;
    int total = CB * T * DMODEL;
    if (idx >= total) return;
    int row = idx / DMODEL;        // bl*T + t
    int d = idx - row * DMODEL;
    int bl = row / T;
    int t = row - bl * T;
    int tok = toks[t * Bdim + bj0 + bl];
    float v = ldw(emb, (size_t)tok * DMODEL + d, isbf) * EMB_SCALE;
    int j = d >> 1;
    float freq = expf(-(float)(2 * j) * (LN10000 / (float)DMODEL));
    float ang = (float)t * freq;
    v += (d & 1) ? cosf(ang) : sinf(ang);
    out[idx] = v;
}

// gather t=0 rows of the encoder chunk into AG at global batch rows
__global__ void gather_t0_kernel(const float* __restrict__ Xc, float* __restrict__ Ag,
                                 int bj0) {
    int bl = blockIdx.x;
    int d = threadIdx.x;
    Ag[(size_t)(bj0 + bl) * DMODEL + d] = Xc[(size_t)bl * T_ENC * DMODEL + d];
    Ag[(size_t)(bj0 + bl) * DMODEL + d + 256] = Xc[(size_t)bl * T_ENC * DMODEL + d + 256];
}

// ---------------------------------------------------------------------------
// MFMA GEMM, split-bf16: C[M,N] = act(A[M,K] @ W[woff..][K,N] + bias[boff..])
// Requires M%64==0, N%64==0, K%64==0. A fp32; W fp32-or-bf16 via dflag.
// 64x64 block tile, BK=64, 256 threads = 4 waves (each 32x32 quadrant).
// ---------------------------------------------------------------------------
#define LDT 72   // LDS row stride in shorts (64 + 8 pad, multiple of 8)

__global__ __launch_bounds__(256) void gemm_mfma_kernel(
    const float* __restrict__ A, const void* __restrict__ W, size_t woff,
    const void* __restrict__ bias, size_t boff, float* __restrict__ C,
    int M, int N, int K, int relu, const int* __restrict__ dflag)
{
    int isbf = dflag[0];
    __shared__ unsigned short Ah[64][LDT], Al[64][LDT];
    __shared__ unsigned short Bh[64][LDT], Bl[64][LDT];   // transposed: [n][k]
    int tid = threadIdx.x;
    int lane = tid & 63, wave = tid >> 6;
    int quad = lane >> 4, l15 = lane & 15;
    int wm = (wave >> 1) * 32, wn = (wave & 1) * 32;
    int row0 = blockIdx.y * 64, col0 = blockIdx.x * 64;

    floatx4 acc[2][2];
    #pragma unroll
    for (int i = 0; i < 2; i++)
        #pragma unroll
        for (int j = 0; j < 2; j++)
            acc[i][j] = (floatx4){0.f, 0.f, 0.f, 0.f};

    int ar = tid >> 2;            // 0..63 A row
    int ac = (tid & 3) * 4;       // A col base within 16
    int bn = tid & 63;            // B col
    int bk4 = (tid >> 6) * 4;     // B k base within 16

    for (int k0 = 0; k0 < K; k0 += 64) {
        // stage A tile (64x64 f32 -> hi/lo bf16)
        const float* arow = A + (size_t)(row0 + ar) * K + k0;
        #pragma unroll
        for (int rep = 0; rep < 4; rep++) {
            int c = ac + rep * 16;
            floatx4 v = *(const floatx4*)(arow + c);
            #pragma unroll
            for (int i = 0; i < 4; i++) {
                unsigned short h = f2bf_rne(v[i]);
                Ah[ar][c + i] = h;
                Al[ar][c + i] = f2bf_rne(v[i] - bf2f(h));
            }
        }
        // stage B tile transposed (64x64) -> Bh/Bl[n][k]
        #pragma unroll
        for (int rep = 0; rep < 4; rep++) {
            int kk = bk4 + rep * 16;
            #pragma unroll
            for (int i = 0; i < 4; i++) {
                float v = ldw(W, woff + (size_t)(k0 + kk + i) * N + col0 + bn, isbf);
                unsigned short h = f2bf_rne(v);
                Bh[bn][kk + i] = h;
                Bl[bn][kk + i] = f2bf_rne(v - bf2f(h));
            }
        }
        __syncthreads();
        #pragma unroll
        for (int ks = 0; ks < 64; ks += 32) {
            short8 fah[2], fal[2], fbh[2], fbl[2];
            #pragma unroll
            for (int i = 0; i < 2; i++) {
                fah[i] = *(const short8*)&Ah[wm + i * 16 + l15][ks + quad * 8];
                fal[i] = *(const short8*)&Al[wm + i * 16 + l15][ks + quad * 8];
                fbh[i] = *(const short8*)&Bh[wn + i * 16 + l15][ks + quad * 8];
                fbl[i] = *(const short8*)&Bl[wn + i * 16 + l15][ks + quad * 8];
            }
            #pragma unroll
            for (int i = 0; i < 2; i++)
                #pragma unroll
                for (int j = 0; j < 2; j++) {
                    acc[i][j] = __builtin_amdgcn_mfma_f32_16x16x32_bf16(fah[i], fbh[j], acc[i][j], 0, 0, 0);
                    acc[i][j] = __builtin_amdgcn_mfma_f32_16x16x32_bf16(fah[i], fbl[j], acc[i][j], 0, 0, 0);
                    acc[i][j] = __builtin_amdgcn_mfma_f32_16x16x32_bf16(fal[i], fbh[j], acc[i][j], 0, 0, 0);
                }
        }
        __syncthreads();
    }
    // epilogue: D[row=quad*4+r][col=l15] per 16x16 tile
    #pragma unroll
    for (int i = 0; i < 2; i++) {
        #pragma unroll
        for (int j = 0; j < 2; j++) {
            int gc = col0 + wn + j * 16 + l15;
            float bv = bias ? ldw(bias, boff + gc, isbf) : 0.f;
            #pragma unroll
            for (int r = 0; r < 4; r++) {
                int gr = row0 + wm + i * 16 + quad * 4 + r;
                float v = acc[i][j][r] + bv;
                if (relu) v = fmaxf(v, 0.f);
                C[(size_t)gr * N + gc] = v;
            }
        }
    }
}

// logits variant: local row gr (bl*T_DEC+t) -> out row t*BT + b0 + bl; f32 out
__global__ __launch_bounds__(256) void gemm_mfma_logits_kernel(
    const float* __restrict__ A, const void* __restrict__ W,
    const void* __restrict__ bias, float* __restrict__ C,
    int N, int K, int b0, const int* __restrict__ dflag)
{
    int isbf = dflag[0];
    __shared__ unsigned short Ah[64][LDT], Al[64][LDT];
    __shared__ unsigned short Bh[64][LDT], Bl[64][LDT];
    int tid = threadIdx.x;
    int lane = tid & 63, wave = tid >> 6;
    int quad = lane >> 4, l15 = lane & 15;
    int wm = (wave >> 1) * 32, wn = (wave & 1) * 32;
    int row0 = blockIdx.y * 64, col0 = blockIdx.x * 64;

    floatx4 acc[2][2];
    #pragma unroll
    for (int i = 0; i < 2; i++)
        #pragma unroll
        for (int j = 0; j < 2; j++)
            acc[i][j] = (floatx4){0.f, 0.f, 0.f, 0.f};

    int ar = tid >> 2;
    int ac = (tid & 3) * 4;
    int bn = tid & 63;
    int bk4 = (tid >> 6) * 4;

    for (int k0 = 0; k0 < K; k0 += 64) {
        const float* arow = A + (size_t)(row0 + ar) * K + k0;
        #pragma unroll
        for (int rep = 0; rep < 4; rep++) {
            int c = ac + rep * 16;
            floatx4 v = *(const floatx4*)(arow + c);
            #pragma unroll
            for (int i = 0; i < 4; i++) {
                unsigned short h = f2bf_rne(v[i]);
                Ah[ar][c + i] = h;
                Al[ar][c + i] = f2bf_rne(v[i] - bf2f(h));
            }
        }
        #pragma unroll
        for (int rep = 0; rep < 4; rep++) {
            int kk = bk4 + rep * 16;
            #pragma unroll
            for (int i = 0; i < 4; i++) {
                float v = ldw(W, (size_t)(k0 + kk + i) * N + col0 + bn, isbf);
                unsigned short h = f2bf_rne(v);
                Bh[bn][kk + i] = h;
                Bl[bn][kk + i] = f2bf_rne(v - bf2f(h));
            }
        }
        __syncthreads();
        #pragma unroll
        for (int ks = 0; ks < 64; ks += 32) {
            short8 fah[2], fal[2], fbh[2], fbl[2];
            #pragma unroll
            for (int i = 0; i < 2; i++) {
                fah[i] = *(const short8*)&Ah[wm + i * 16 + l15][ks + quad * 8];
                fal[i] = *(const short8*)&Al[wm + i * 16 + l15][ks + quad * 8];
                fbh[i] = *(const short8*)&Bh[wn + i * 16 + l15][ks + quad * 8];
                fbl[i] = *(const short8*)&Bl[wn + i * 16 + l15][ks + quad * 8];
            }
            #pragma unroll
            for (int i = 0; i < 2; i++)
                #pragma unroll
                for (int j = 0; j < 2; j++) {
                    acc[i][j] = __builtin_amdgcn_mfma_f32_16x16x32_bf16(fah[i], fbh[j], acc[i][j], 0, 0, 0);
                    acc[i][j] = __builtin_amdgcn_mfma_f32_16x16x32_bf16(fah[i], fbl[j], acc[i][j], 0, 0, 0);
                    acc[i][j] = __builtin_amdgcn_mfma_f32_16x16x32_bf16(fal[i], fbh[j], acc[i][j], 0, 0, 0);
                }
        }
        __syncthreads();
    }
    #pragma unroll
    for (int i = 0; i < 2; i++) {
        #pragma unroll
        for (int j = 0; j < 2; j++) {
            int gc = col0 + wn + j * 16 + l15;
            float bv = ldw(bias, gc, isbf);
            #pragma unroll
            for (int r = 0; r < 4; r++) {
                int gr = row0 + wm + i * 16 + quad * 4 + r;   // bl*1024 + t
                int out_row = ((gr & (T_DEC - 1)) * BT) + b0 + (gr >> 10);
                C[(size_t)out_row * N + gc] = acc[i][j][r] + bv;
            }
        }
    }
}

// attention within chunk: one block per (t, bl, h); qkv rows local bl*T + t
__global__ __launch_bounds__(256) void attn_kernel(
    const float* __restrict__ qkv, float* __restrict__ out,
    int T, int causal)
{
    __shared__ float qv[DH];
    __shared__ float sc[1024];
    __shared__ float red[256];
    __shared__ float part[256];
    int t = blockIdx.x;
    int bh = blockIdx.y;
    int bl = bh / NH, h = bh - (bh / NH) * NH;
    int tid = threadIdx.x;
    size_t row = (size_t)bl * T + t;
    const float* qp = qkv + row * (3 * DMODEL) + h * DH;
    if (tid < DH) qv[tid] = qp[tid];
    __syncthreads();
    int Tlim = causal ? (t + 1) : T;
    float lmax = -1e30f;
    for (int s = tid; s < Tlim; s += 256) {
        const float* kp = qkv + ((size_t)bl * T + s) * (3 * DMODEL) + DMODEL + h * DH;
        float dsum = 0.f;
        #pragma unroll
        for (int d = 0; d < DH; d++) dsum += qv[d] * kp[d];
        dsum *= 0.125f;
        sc[s] = dsum;
        lmax = fmaxf(lmax, dsum);
    }
    red[tid] = lmax; __syncthreads();
    for (int o = 128; o > 0; o >>= 1) {
        if (tid < o) red[tid] = fmaxf(red[tid], red[tid + o]);
        __syncthreads();
    }
    float m = red[0]; __syncthreads();
    float lsum = 0.f;
    for (int s = tid; s < Tlim; s += 256) {
        float e = expf(sc[s] - m);
        sc[s] = e;
        lsum += e;
    }
    red[tid] = lsum; __syncthreads();
    for (int o = 128; o > 0; o >>= 1) {
        if (tid < o) red[tid] += red[tid + o];
        __syncthreads();
    }
    float inv = 1.f / red[0];
    int d = tid & 63, grp = tid >> 6;
    float a = 0.f;
    for (int s = grp; s < Tlim; s += 4)
        a += sc[s] * qkv[((size_t)bl * T + s) * (3 * DMODEL) + 2 * DMODEL + h * DH + d];
    part[tid] = a; __syncthreads();
    if (tid < 64) {
        float o = (part[tid] + part[tid + 64] + part[tid + 128] + part[tid + 192]) * inv;
        out[row * DMODEL + h * DH + tid] = o;
    }
}

// out = LN(a+c) * g[goff..] + b[goff..]
__global__ __launch_bounds__(256) void ln_res_kernel(
    const float* __restrict__ a, const float* __restrict__ c,
    const void* __restrict__ g, const void* __restrict__ be, size_t goff,
    float* __restrict__ out, const int* __restrict__ dflag)
{
    int isbf = dflag[0];
    __shared__ float red[256];
    int row = blockIdx.x, tid = threadIdx.x;
    size_t base = (size_t)row * DMODEL;
    float x0 = a[base + tid] + c[base + tid];
    float x1 = a[base + tid + 256] + c[base + tid + 256];
    red[tid] = x0 + x1; __syncthreads();
    for (int o = 128; o > 0; o >>= 1) {
        if (tid < o) red[tid] += red[tid + o];
        __syncthreads();
    }
    float mean = red[0] * (1.f / DMODEL); __syncthreads();
    float d0 = x0 - mean, d1 = x1 - mean;
    red[tid] = d0 * d0 + d1 * d1; __syncthreads();
    for (int o = 128; o > 0; o >>= 1) {
        if (tid < o) red[tid] += red[tid + o];
        __syncthreads();
    }
    float rstd = rsqrtf(red[0] * (1.f / DMODEL) + 1e-5f);
    out[base + tid] = d0 * rstd * ldw(g, goff + tid, isbf) + ldw(be, goff + tid, isbf);
    out[base + tid + 256] = d1 * rstd * ldw(g, goff + tid + 256, isbf) + ldw(be, goff + tid + 256, isbf);
}

__global__ __launch_bounds__(64) void vq_kernel(
    const float* __restrict__ mu, const void* __restrict__ codebook,
    float* __restrict__ z, float* __restrict__ acc, const int* __restrict__ dflag)
{
    int isbf = dflag[0];
    __shared__ float cb[NCODES * 2];
    __shared__ float red[64];
    int r = blockIdx.x, tid = threadIdx.x;
    for (int i = tid; i < NCODES * 2; i += 64) cb[i] = ldw(codebook, i, isbf);
    __syncthreads();
    float g0 = mu[r * DLAT + 2 * tid];
    float g1 = mu[r * DLAT + 2 * tid + 1];
    float gg = g0 * g0 + g1 * g1;
    float best = 3.4e38f; int bi = 0;
    for (int c = 0; c < NCODES; c++) {
        float c0 = cb[2 * c], c1 = cb[2 * c + 1];
        float d2 = (gg - 2.f * (g0 * c0 + g1 * c1)) + (c0 * c0 + c1 * c1);
        if (d2 < best) { best = d2; bi = c; }
    }
    float q0 = cb[2 * bi], q1 = cb[2 * bi + 1];
    z[r * DLAT + 2 * tid] = q0;
    z[r * DLAT + 2 * tid + 1] = q1;
    float dv = (q0 - g0) * (q0 - g0) + (q1 - g1) * (q1 - g1);
    red[tid] = dv; __syncthreads();
    for (int o = 32; o > 0; o >>= 1) {
        if (tid < o) red[tid] += red[tid + o];
        __syncthreads();
    }
    if (tid == 0) atomicAdd(acc, red[0]);
}

__global__ void diff_kernel(const float* __restrict__ acc, float* __restrict__ dst) {
    dst[0] = 2.f * acc[0] / 16384.f;
}

// seg scatter for one decoder chunk: dsc[(bl*T_DEC + t)*DLAT + d], b = b0+bl
__global__ __launch_bounds__(128) void seg_kernel(
    const int* __restrict__ pos, const float* __restrict__ z,
    float* __restrict__ dsc, int b0)
{
    int t = blockIdx.x, bl = blockIdx.y;
    int b = b0 + bl;
    __shared__ int sseg;
    if (threadIdx.x == 0) {
        int cnt = 0;
        for (int i = 0; i < NSEQ + 1; i++) cnt += (pos[b * (NSEQ + 1) + i] <= t) ? 1 : 0;
        sseg = cnt - 1;
    }
    __syncthreads();
    int seg = sseg;
    float v = 0.f;
    if (seg >= 0 && seg < NSEQ) v = z[(b * NSEQ + seg) * DLAT + threadIdx.x];
    dsc[((size_t)bl * T_DEC + t) * DLAT + threadIdx.x] = v;
}

extern "C" void kernel_launch(void* const* d_in, const int* in_sizes, int n_in,
                              void* d_out, int out_size, void* d_ws, size_t ws_size,
                              hipStream_t stream)
{
    const int*  enc_inp = (const int*)d_in[0];
    const int*  dec_inp = (const int*)d_in[1];
    const int*  seq_pos = (const int*)d_in[2];
    const void* emb   = d_in[3];
    const void* eWqkv = d_in[4];  const void* eWo  = d_in[5];
    const void* eln1g = d_in[6];  const void* eln1b = d_in[7];
    const void* eln2g = d_in[8];  const void* eln2b = d_in[9];
    const void* eW1   = d_in[10]; const void* eb1  = d_in[11];
    const void* eW2   = d_in[12]; const void* eb2  = d_in[13];
    const void* dWqkv = d_in[14]; const void* dWo  = d_in[15];
    const void* dln1g = d_in[16]; const void* dln1b = d_in[17];
    const void* dln2g = d_in[18]; const void* dln2b = d_in[19];
    const void* dW1   = d_in[20]; const void* db1  = d_in[21];
    const void* dW2   = d_in[22]; const void* db2  = d_in[23];
    const void* W_mu  = d_in[24]; const void* b_mu = d_in[25];
    const void* cbk   = d_in[26];
    const void* seg_W = d_in[27]; const void* seg_b = d_in[28];
    const void* W_out = d_in[29]; const void* b_out = d_in[30];

    float* outf = (float*)d_out;
    float* out_mu     = outf;
    float* out_z      = outf + 16384;
    float* out_diff   = outf + 32768;
    float* out_logits = outf + 32769;

    bool order_ok = (n_in == 31) &&
        in_sizes[0] == 16384 && in_sizes[1] == 8192 && in_sizes[2] == 136 &&
        in_sizes[3] == 524288 && in_sizes[4] == 3145728 && in_sizes[5] == 1048576 &&
        in_sizes[10] == 4194304 && in_sizes[14] == 4718592 && in_sizes[15] == 1572864 &&
        in_sizes[24] == 65536 && in_sizes[25] == 128 && in_sizes[26] == 4096 &&
        in_sizes[29] == 524288 && in_sizes[30] == 1024;
    if (!order_ok) {
        fill_kernel<<<64, 256, 0, stream>>>(out_mu, 100.0f, 16384);
        return;
    }

    // ---- compact workspace layout (floats); total ~35 MB ----
    float* ws  = (float*)d_ws;
    float* XC  = ws;                    // [2048,512]  chunk stream
    float* SPC = ws + 1048576;          // [2048,512]  seg_proj chunk
    float* TIN = ws + 2097152;          // [2048,512]  dec layer input
    float* QKV = ws + 3145728;          // [2048,1536]
    float* AO  = ws + 6291456;          // [2048,512]
    float* H   = ws + 3145728;          // [2048,2048] overlays QKV+AO (FFN phase)
    float* P   = ws + 7340032;          // [2048,512]
    float* DSC = ws + 8388608;          // [2048,128]
    float* AG  = ws + 8650752;          // [128,512]
    float* MU  = ws + 8716288;          // [128,128]
    float* Z   = ws + 8732672;          // [128,128]
    float* ACC = ws + 8749056;          // [1]
    int*   FLG = (int*)(ws + 8749057);  // [1]

    detect_kernel<<<1, 64, 0, stream>>>((const unsigned int*)eln1g, FLG, ACC);

    // ================= encoder: 8 chunks × (embed → 4 layers → gather) ======
    for (int c = 0; c < BENC / ENC_CB; c++) {
        int bj0 = c * ENC_CB;
        embed_kernel<<<(MC * DMODEL + 255) / 256, 256, 0, stream>>>(
            enc_inp, emb, XC, T_ENC, BENC, bj0, ENC_CB, FLG);
        for (int i = 0; i < ENC_L; i++) {
            size_t oQ  = (size_t)i * DMODEL * 3 * DMODEL;
            size_t oO  = (size_t)i * DMODEL * DMODEL;
            size_t o1  = (size_t)i * DMODEL * DFF;
            size_t o2  = (size_t)i * DFF * DMODEL;
            size_t oLn = (size_t)i * DMODEL;
            size_t oB1 = (size_t)i * DFF;
            gemm_mfma_kernel<<<dim3(3 * DMODEL / 64, MC / 64), 256, 0, stream>>>(
                XC, eWqkv, oQ, nullptr, 0, QKV, MC, 3 * DMODEL, DMODEL, 0, FLG);
            attn_kernel<<<dim3(T_ENC, ENC_CB * NH), 256, 0, stream>>>(QKV, AO, T_ENC, 0);
            gemm_mfma_kernel<<<dim3(DMODEL / 64, MC / 64), 256, 0, stream>>>(
                AO, eWo, oO, nullptr, 0, P, MC, DMODEL, DMODEL, 0, FLG);
            ln_res_kernel<<<MC, 256, 0, stream>>>(XC, P, eln1g, eln1b, oLn, XC, FLG);
            gemm_mfma_kernel<<<dim3(DFF / 64, MC / 64), 256, 0, stream>>>(
                XC, eW1, o1, eb1, oB1, H, MC, DFF, DMODEL, 1, FLG);
            gemm_mfma_kernel<<<dim3(DMODEL / 64, MC / 64), 256, 0, stream>>>(
                H, eW2, o2, eb2, oLn, P, MC, DMODEL, DFF, 0, FLG);
            ln_res_kernel<<<MC, 256, 0, stream>>>(XC, P, eln2g, eln2b, oLn, XC, FLG);
        }
        gather_t0_kernel<<<ENC_CB, 256, 0, stream>>>(XC, AG, bj0);
    }

    // ================= VQ =================
    gemm_mfma_kernel<<<dim3(DLAT / 64, BENC / 64), 256, 0, stream>>>(
        AG, W_mu, 0, b_mu, 0, MU, BENC, DLAT, DMODEL, 0, FLG);
    vq_kernel<<<BENC, 64, 0, stream>>>(MU, cbk, Z, ACC, FLG);
    copy_kernel<<<64, 256, 0, stream>>>(MU, out_mu, 16384);
    copy_kernel<<<64, 256, 0, stream>>>(Z, out_z, 16384);
    diff_kernel<<<1, 1, 0, stream>>>(ACC, out_diff);

    // ================= decoder: 4 chunks × (seg → SP → embed → 6 layers → logits)
    for (int c = 0; c < BT / DEC_CB; c++) {
        int b0 = c * DEC_CB;
        seg_kernel<<<dim3(T_DEC, DEC_CB), 128, 0, stream>>>(seq_pos, Z, DSC, b0);
        gemm_mfma_kernel<<<dim3(DMODEL / 64, MC / 64), 256, 0, stream>>>(
            DSC, seg_W, 0, seg_b, 0, SPC, MC, DMODEL, DLAT, 0, FLG);
        embed_kernel<<<(MC * DMODEL + 255) / 256, 256, 0, stream>>>(
            dec_inp, emb, XC, T_DEC, BT, b0, DEC_CB, FLG);
        for (int i = 0; i < DEC_L; i++) {
            size_t oQ  = (size_t)i * DMODEL * 3 * DMODEL;
            size_t oO  = (size_t)i * DMODEL * DMODEL;
            size_t o1  = (size_t)i * DMODEL * DFF;
            size_t o2  = (size_t)i * DFF * DMODEL;
            size_t oLn = (size_t)i * DMODEL;
            size_t oB1 = (size_t)i * DFF;
            add_kernel<<<(MC * DMODEL + 255) / 256, 256, 0, stream>>>(XC, SPC, TIN, MC * DMODEL);
            gemm_mfma_kernel<<<dim3(3 * DMODEL / 64, MC / 64), 256, 0, stream>>>(
                TIN, dWqkv, oQ, nullptr, 0, QKV, MC, 3 * DMODEL, DMODEL, 0, FLG);
            attn_kernel<<<dim3(T_DEC, DEC_CB * NH), 256, 0, stream>>>(QKV, AO, T_DEC, 1);
            gemm_mfma_kernel<<<dim3(DMODEL / 64, MC / 64), 256, 0, stream>>>(
                AO, dWo, oO, nullptr, 0, P, MC, DMODEL, DMODEL, 0, FLG);
            ln_res_kernel<<<MC, 256, 0, stream>>>(TIN, P, dln1g, dln1b, oLn, TIN, FLG);
            gemm_mfma_kernel<<<dim3(DFF / 64, MC / 64), 256, 0, stream>>>(
                TIN, dW1, o1, db1, oB1, H, MC, DFF, DMODEL, 1, FLG);
            gemm_mfma_kernel<<<dim3(DMODEL / 64, MC / 64), 256, 0, stream>>>(
                H, dW2, o2, db2, oLn, P, MC, DMODEL, DFF, 0, FLG);
            ln_res_kernel<<<MC, 256, 0, stream>>>(TIN, P, dln2g, dln2b, oLn, XC, FLG);
        }
        gemm_mfma_logits_kernel<<<dim3(NTOK / 64, MC / 64), 256, 0, stream>>>(
            XC, W_out, b_out, out_logits, NTOK, DMODEL, b0, FLG);
    }
}